// Round 3
// baseline (630.414 us; speedup 1.0000x reference)
//
#include <hip/hip_runtime.h>
#include <hip/hip_bf16.h>
#include <math.h>

#define SEQ 2048
#define BATCH 4
#define DM 512
#define NH 8
#define HD 64
#define HID 2048
#define ROWS (BATCH * SEQ)

typedef __attribute__((ext_vector_type(8))) short short8;
typedef __attribute__((ext_vector_type(4))) float f32x4;

__device__ __forceinline__ short f2bf(float f) {
    unsigned u = __float_as_uint(f);
    u += 0x7fff + ((u >> 16) & 1);   // RNE
    return (short)(u >> 16);
}

// async global->LDS DMA, 16 B per lane; LDS dest must be wave-uniform base + lane*16
__device__ __forceinline__ void gl2lds16(const void* g, void* l) {
    __builtin_amdgcn_global_load_lds(
        (const __attribute__((address_space(1))) void*)g,
        (__attribute__((address_space(3))) void*)l, 16, 0, 0);
}

// ---------------- weight transpose + cast: W[K][N] fp32 -> Wt[N][K] bf16 ----
__global__ __launch_bounds__(256) void tcast_k(const float* __restrict__ W,
                                               short* __restrict__ Wt,
                                               int K, int N) {
    __shared__ float tile[32][33];
    int tx = threadIdx.x, ty = threadIdx.y;
    int n0 = blockIdx.x * 32, k0 = blockIdx.y * 32;
#pragma unroll
    for (int i = 0; i < 4; ++i)
        tile[ty + i * 8][tx] = W[(size_t)(k0 + ty + i * 8) * N + n0 + tx];
    __syncthreads();
#pragma unroll
    for (int i = 0; i < 4; ++i)
        Wt[(size_t)(n0 + ty + i * 8) * K + k0 + tx] = f2bf(tile[tx][ty + i * 8]);
}

// ---------------- layernorm: fp32 [rows][512] -> bf16, one wave per row -----
__global__ __launch_bounds__(256) void ln_k(const float* __restrict__ X,
                                            const float* __restrict__ g,
                                            const float* __restrict__ bta,
                                            short* __restrict__ Y) {
    int t = threadIdx.x;
    int wv = t >> 6, ln = t & 63;
    size_t row = (size_t)blockIdx.x * 4 + wv;
    const float* xr = X + row * DM;
    float4 v0 = *(const float4*)(xr + ln * 4);
    float4 v1 = *(const float4*)(xr + 256 + ln * 4);
    float s = v0.x + v0.y + v0.z + v0.w + v1.x + v1.y + v1.z + v1.w;
    float q = v0.x * v0.x + v0.y * v0.y + v0.z * v0.z + v0.w * v0.w +
              v1.x * v1.x + v1.y * v1.y + v1.z * v1.z + v1.w * v1.w;
#pragma unroll
    for (int off = 1; off < 64; off <<= 1) {
        s += __shfl_xor(s, off);
        q += __shfl_xor(q, off);
    }
    float mean = s * (1.0f / 512.0f);
    float var = q * (1.0f / 512.0f) - mean * mean;
    float rstd = rsqrtf(var + 1e-5f);
    int c0 = ln * 4, c1 = 256 + ln * 4;
    ushort4 o0, o1;
    o0.x = (unsigned short)f2bf((v0.x - mean) * rstd * g[c0 + 0] + bta[c0 + 0]);
    o0.y = (unsigned short)f2bf((v0.y - mean) * rstd * g[c0 + 1] + bta[c0 + 1]);
    o0.z = (unsigned short)f2bf((v0.z - mean) * rstd * g[c0 + 2] + bta[c0 + 2]);
    o0.w = (unsigned short)f2bf((v0.w - mean) * rstd * g[c0 + 3] + bta[c0 + 3]);
    o1.x = (unsigned short)f2bf((v1.x - mean) * rstd * g[c1 + 0] + bta[c1 + 0]);
    o1.y = (unsigned short)f2bf((v1.y - mean) * rstd * g[c1 + 1] + bta[c1 + 1]);
    o1.z = (unsigned short)f2bf((v1.z - mean) * rstd * g[c1 + 2] + bta[c1 + 2]);
    o1.w = (unsigned short)f2bf((v1.w - mean) * rstd * g[c1 + 3] + bta[c1 + 3]);
    *(ushort4*)((unsigned short*)Y + row * DM + c0) = o0;
    *(ushort4*)((unsigned short*)Y + row * DM + c1) = o1;
}

// ---------------- GEMM: C[M][N] = A[M][K] * Bt[N][K]^T, bf16 MFMA ----------
// m97 structure; TN = 128 (4x4 acc) or 64 (4x2 acc, 2x grid parallelism).
// EPI 0: bf16 out = C + bias ; EPI 1: bf16 out = gelu(C+bias) ;
// EPI 2: fp32 out = res + (C + bias) * gamma
template <int EPI, int TN>
__global__ __launch_bounds__(256) void gemm_bt(const short* __restrict__ A,
                                               const short* __restrict__ Bt,
                                               const float* __restrict__ bias,
                                               const float* __restrict__ gamma,
                                               const float* __restrict__ res,
                                               void* __restrict__ Cout,
                                               int M, int N, int K) {
    constexpr int NI = TN / 32;   // B-fragment sets per wave
    __shared__ __attribute__((aligned(16))) short As[128][32];
    __shared__ __attribute__((aligned(16))) short Bs[TN][32];
    int t = threadIdx.x;
    int w = t >> 6, ln = t & 63;
    int quad = ln >> 4, l15 = ln & 15;
    int n0 = blockIdx.x * TN, m0 = blockIdx.y * 128;
    int wm = (w & 1) * 64, wn = (w >> 1) * (TN / 2);

    int srow0 = w * 32 + (ln >> 2);     // A staging: rows w*32 .. w*32+32
    int srow1 = srow0 + 16;
    int srowB = w * 16 + (ln >> 2);     // B staging for TN=64
    int schunk = (ln & 3) * 8;
    const short* Ag0 = A + (size_t)(m0 + srow0) * K + schunk;
    const short* Ag1 = A + (size_t)(m0 + srow1) * K + schunk;

    f32x4 acc[4][NI];
#pragma unroll
    for (int i = 0; i < 4; ++i)
#pragma unroll
        for (int j = 0; j < NI; ++j) acc[i][j] = (f32x4){0.f, 0.f, 0.f, 0.f};

    for (int k0 = 0; k0 < K; k0 += 32) {
        __syncthreads();
        gl2lds16(Ag0 + k0, &As[srow0][schunk]);
        gl2lds16(Ag1 + k0, &As[srow1][schunk]);
        if (TN == 128) {
            gl2lds16(Bt + (size_t)(n0 + srow0) * K + k0 + schunk, &Bs[srow0 & (TN - 1)][schunk]);
            gl2lds16(Bt + (size_t)(n0 + srow1) * K + k0 + schunk, &Bs[srow1 & (TN - 1)][schunk]);
        } else {
            gl2lds16(Bt + (size_t)(n0 + srowB) * K + k0 + schunk, &Bs[srowB & (TN - 1)][schunk]);
        }
        __syncthreads();
        short8 af[4], bf[NI];
#pragma unroll
        for (int mi = 0; mi < 4; ++mi)
            af[mi] = *(const short8*)&As[wm + mi * 16 + l15][quad * 8];
#pragma unroll
        for (int ni = 0; ni < NI; ++ni)
            bf[ni] = *(const short8*)&Bs[wn + ni * 16 + l15][quad * 8];
#pragma unroll
        for (int mi = 0; mi < 4; ++mi)
#pragma unroll
            for (int ni = 0; ni < NI; ++ni)
                acc[mi][ni] = __builtin_amdgcn_mfma_f32_16x16x32_bf16(
                    af[mi], bf[ni], acc[mi][ni], 0, 0, 0);
    }

#pragma unroll
    for (int mi = 0; mi < 4; ++mi) {
#pragma unroll
        for (int ni = 0; ni < NI; ++ni) {
#pragma unroll
            for (int r = 0; r < 4; ++r) {
                int row = m0 + wm + mi * 16 + quad * 4 + r;
                int col = n0 + wn + ni * 16 + l15;
                float v = acc[mi][ni][r] + bias[col];
                if (EPI == 0) {
                    ((short*)Cout)[(size_t)row * N + col] = f2bf(v);
                } else if (EPI == 1) {
                    float gg = 0.5f * v * (1.0f + erff(v * 0.70710678118654752f));
                    ((short*)Cout)[(size_t)row * N + col] = f2bf(gg);
                } else {
                    ((float*)Cout)[(size_t)row * N + col] =
                        fmaf(v, gamma[col], res[(size_t)row * N + col]);
                }
            }
        }
    }
}

// ---------------- flash attention v3: block = (h, 32-q-tile), 4 batches -----
// 512 threads = 8 waves; wave w: batch = w&3, q-group = w>>2 (16 q rows).
// Bias tile read once per block straight to registers (f32, coalesced);
// K frags direct from global (L2-resident per XCD: h = blockIdx&7);
// V staged+transposed in LDS; K/V/bias software-prefetched one jt ahead.
// No-max softmax; row-sums via ones-column MFMA.
__global__ __launch_bounds__(512) void attn_k(const short* __restrict__ qkv,
                                              const float* __restrict__ bias,
                                              short* __restrict__ Aout) {
    __shared__ __attribute__((aligned(16))) short Vt[BATCH][64][72];
    __shared__ __attribute__((aligned(16))) short Ps[8][16][72];
    int t = threadIdx.x;
    int w = t >> 6, ln = t & 63, quad = ln >> 4, l15 = ln & 15;
    int h = blockIdx.x & 7, qt = blockIdx.x >> 3;
    int b = w & 3, qg = w >> 2;
    int qb = qt * 32 + qg * 16;               // wave's 16-q base
    const size_t cbase = (size_t)b * SEQ * 1536;

    // Q fragment (B-operand): Q[qb + l15][d]
    const short* qrow = qkv + cbase + (size_t)(qb + l15) * 1536 + h * 64;
    short8 qf0 = *(const short8*)(qrow + quad * 8);
    short8 qf1 = *(const short8*)(qrow + 32 + quad * 8);

    // K fragment base (A-operand): K[j0 + ni*16 + l15][quad*8 (+32)]
    const short* kbase = qkv + cbase + 512 + h * 64 + (size_t)l15 * 1536 + quad * 8;
    // bias row base for this lane's q (C-layout col q = l15)
    const float* bias_q = bias + (size_t)h * SEQ * SEQ + (size_t)(qb + l15) * SEQ;

    // V staging map: batch sb (128 threads), key-pair kp, d-chunk vh*16
    int sb = t >> 7, r7 = t & 127, kp = r7 & 31, vh = r7 >> 5;
    const short* vbase = qkv + (size_t)sb * SEQ * 1536 + 1024 + h * 64 + vh * 16;

    short8 ones;
#pragma unroll
    for (int i = 0; i < 8; ++i) ones[i] = (short)0x3F80;  // bf16 1.0

    f32x4 o[4], ol;
#pragma unroll
    for (int db = 0; db < 4; ++db) o[db] = (f32x4){0.f, 0.f, 0.f, 0.f};
    ol = (f32x4){0.f, 0.f, 0.f, 0.f};

    // ---- prefetch jt = 0 ----
    short8 kf0[4], kf1[4];
    float4 bb[4];
    union { float4 f; short s[8]; } va0, va1, vb0, vb1;
    {
        const short* kr = kbase;
#pragma unroll
        for (int ni = 0; ni < 4; ++ni) {
            kf0[ni] = *(const short8*)(kr + (size_t)ni * 16 * 1536);
            kf1[ni] = *(const short8*)(kr + (size_t)ni * 16 * 1536 + 32);
        }
#pragma unroll
        for (int ni = 0; ni < 4; ++ni)
            bb[ni] = *(const float4*)(bias_q + ni * 16 + quad * 4);
        const short* vr = vbase + (size_t)(2 * kp) * 1536;
        va0.f = *(const float4*)vr;
        va1.f = *(const float4*)(vr + 8);
        vb0.f = *(const float4*)(vr + 1536);
        vb1.f = *(const float4*)(vr + 1536 + 8);
    }

    for (int jt = 0; jt < 32; ++jt) {
        __syncthreads();   // previous Vt fully consumed
        // write Vt(jt): Vt[sb][vh*16+j][2kp] ; banks = (36j + kp) % 32 -> 2-way free
#pragma unroll
        for (int j = 0; j < 8; ++j) {
            ushort2 pr;
            pr.x = (unsigned short)va0.s[j];
            pr.y = (unsigned short)vb0.s[j];
            *(ushort2*)&Vt[sb][vh * 16 + j][2 * kp] = pr;
        }
#pragma unroll
        for (int j = 0; j < 8; ++j) {
            ushort2 pr;
            pr.x = (unsigned short)va1.s[j];
            pr.y = (unsigned short)vb1.s[j];
            *(ushort2*)&Vt[sb][vh * 16 + 8 + j][2 * kp] = pr;
        }
        __syncthreads();

        int jn = (jt < 31) ? jt + 1 : jt;   // prefetch target (dummy reload on last)

        // S^T = K Q^T : lane holds (key = ni*16 + quad*4 + r, q = l15)
        f32x4 s4[4];
#pragma unroll
        for (int ni = 0; ni < 4; ++ni) {
            s4[ni] = (f32x4){0.f, 0.f, 0.f, 0.f};
            s4[ni] = __builtin_amdgcn_mfma_f32_16x16x32_bf16(kf0[ni], qf0, s4[ni], 0, 0, 0);
            s4[ni] = __builtin_amdgcn_mfma_f32_16x16x32_bf16(kf1[ni], qf1, s4[ni], 0, 0, 0);
        }
        // prefetch K(jn) (WAR on kf: issues without stall)
        {
            const short* kr = kbase + (size_t)jn * 64 * 1536;
#pragma unroll
            for (int ni = 0; ni < 4; ++ni) {
                kf0[ni] = *(const short8*)(kr + (size_t)ni * 16 * 1536);
                kf1[ni] = *(const short8*)(kr + (size_t)ni * 16 * 1536 + 32);
            }
            const short* vr = vbase + (size_t)(jn * 64 + 2 * kp) * 1536;
            va0.f = *(const float4*)vr;
            va1.f = *(const float4*)(vr + 8);
            vb0.f = *(const float4*)(vr + 1536);
            vb1.f = *(const float4*)(vr + 1536 + 8);
        }
        // no-max softmax using bias regs; write P (b64, ~2-way)
#pragma unroll
        for (int ni = 0; ni < 4; ++ni) {
            float p0 = __expf(fmaf(s4[ni][0], 0.125f, bb[ni].x));
            float p1 = __expf(fmaf(s4[ni][1], 0.125f, bb[ni].y));
            float p2 = __expf(fmaf(s4[ni][2], 0.125f, bb[ni].z));
            float p3 = __expf(fmaf(s4[ni][3], 0.125f, bb[ni].w));
            ushort4 pk;
            pk.x = (unsigned short)f2bf(p0);
            pk.y = (unsigned short)f2bf(p1);
            pk.z = (unsigned short)f2bf(p2);
            pk.w = (unsigned short)f2bf(p3);
            *(ushort4*)&Ps[w][l15][ni * 16 + quad * 4] = pk;
        }
        // prefetch bias(jn) after last use
#pragma unroll
        for (int ni = 0; ni < 4; ++ni)
            bb[ni] = *(const float4*)(bias_q + jn * 64 + ni * 16 + quad * 4);
        // O += P V ; l += P 1  (wave-private Ps: lgkmcnt ordering, no barrier)
#pragma unroll
        for (int kk = 0; kk < 2; ++kk) {
            short8 ap = *(const short8*)&Ps[w][l15][kk * 32 + quad * 8];
#pragma unroll
            for (int db = 0; db < 4; ++db) {
                short8 vv = *(const short8*)&Vt[b][db * 16 + l15][kk * 32 + quad * 8];
                o[db] = __builtin_amdgcn_mfma_f32_16x16x32_bf16(ap, vv, o[db], 0, 0, 0);
            }
            ol = __builtin_amdgcn_mfma_f32_16x16x32_bf16(ap, ones, ol, 0, 0, 0);
        }
    }
    // epilogue: O row q = qb + quad*4 + r, col d = db*16 + l15
#pragma unroll
    for (int r = 0; r < 4; ++r) {
        float inv = 1.0f / ol[r];
        int qrow_g = b * SEQ + qb + quad * 4 + r;
#pragma unroll
        for (int db = 0; db < 4; ++db) {
            Aout[(size_t)qrow_g * DM + h * 64 + db * 16 + l15] =
                f2bf(o[db][r] * inv);
        }
    }
}

extern "C" void kernel_launch(void* const* d_in, const int* in_sizes, int n_in,
                              void* d_out, int out_size, void* d_ws, size_t ws_size,
                              hipStream_t stream) {
    const float* x      = (const float*)d_in[0];
    const float* bias   = (const float*)d_in[1];
    const float* qkv_w  = (const float*)d_in[2];
    const float* qkv_b  = (const float*)d_in[3];
    const float* out_w  = (const float*)d_in[4];
    const float* out_b  = (const float*)d_in[5];
    const float* ln1_w  = (const float*)d_in[6];
    const float* ln1_b  = (const float*)d_in[7];
    const float* ln2_w  = (const float*)d_in[8];
    const float* ln2_b  = (const float*)d_in[9];
    const float* ffn_w1 = (const float*)d_in[10];
    const float* ffn_b1 = (const float*)d_in[11];
    const float* ffn_w2 = (const float*)d_in[12];
    const float* ffn_b2 = (const float*)d_in[13];
    const float* gamma1 = (const float*)d_in[14];
    const float* gamma2 = (const float*)d_in[15];
    float* out = (float*)d_out;

    short* wqkvT = (short*)d_ws;                         // [1536][512]
    short* woutT = wqkvT + (size_t)1536 * 512;           // [512][512]
    short* w1T   = woutT + (size_t)512 * 512;            // [2048][512]
    short* w2T   = w1T + (size_t)2048 * 512;             // [512][2048]
    short* y1    = w2T + (size_t)512 * 2048;             // [8192][512]
    short* qkvB  = y1 + (size_t)ROWS * DM;               // [8192][1536]
    short* aoutB = qkvB + (size_t)ROWS * 1536;           // [8192][512]
    float* x1    = (float*)(aoutB + (size_t)ROWS * DM);  // [8192][512] fp32
    short* hB    = qkvB;  // ffn hidden [8192][2048] reuses qkv+aout region

    tcast_k<<<dim3(1536 / 32, 512 / 32), dim3(32, 8), 0, stream>>>(qkv_w, wqkvT, 512, 1536);
    tcast_k<<<dim3(512 / 32, 512 / 32), dim3(32, 8), 0, stream>>>(out_w, woutT, 512, 512);
    tcast_k<<<dim3(2048 / 32, 512 / 32), dim3(32, 8), 0, stream>>>(ffn_w1, w1T, 512, 2048);
    tcast_k<<<dim3(512 / 32, 2048 / 32), dim3(32, 8), 0, stream>>>(ffn_w2, w2T, 2048, 512);

    ln_k<<<ROWS / 4, 256, 0, stream>>>(x, ln1_w, ln1_b, y1);
    gemm_bt<0, 128><<<dim3(1536 / 128, ROWS / 128), 256, 0, stream>>>(
        y1, wqkvT, qkv_b, nullptr, nullptr, qkvB, ROWS, 1536, 512);
    attn_k<<<512, 512, 0, stream>>>(qkvB, bias, aoutB);
    gemm_bt<2, 64><<<dim3(512 / 64, ROWS / 128), 256, 0, stream>>>(
        aoutB, woutT, out_b, gamma1, x, x1, ROWS, 512, 512);
    ln_k<<<ROWS / 4, 256, 0, stream>>>(x1, ln2_w, ln2_b, y1);
    gemm_bt<1, 128><<<dim3(2048 / 128, ROWS / 128), 256, 0, stream>>>(
        y1, w1T, ffn_b1, nullptr, nullptr, hB, ROWS, 2048, 512);
    gemm_bt<2, 64><<<dim3(512 / 64, ROWS / 128), 256, 0, stream>>>(
        hB, w2T, ffn_b2, gamma2, x1, out, ROWS, 512, 2048);
}

// Round 4
// 446.853 us; speedup vs baseline: 1.4108x; 1.4108x over previous
//
#include <hip/hip_runtime.h>
#include <hip/hip_bf16.h>
#include <math.h>

#define SEQ 2048
#define BATCH 4
#define DM 512
#define NH 8
#define HD 64
#define HID 2048
#define ROWS (BATCH * SEQ)

typedef __attribute__((ext_vector_type(8))) short short8;
typedef __attribute__((ext_vector_type(4))) float f32x4;

__device__ __forceinline__ short f2bf(float f) {
    unsigned u = __float_as_uint(f);
    u += 0x7fff + ((u >> 16) & 1);   // RNE
    return (short)(u >> 16);
}

// async global->LDS DMA, 16 B per lane; LDS dest must be wave-uniform base + lane*16
__device__ __forceinline__ void gl2lds16(const void* g, void* l) {
    __builtin_amdgcn_global_load_lds(
        (const __attribute__((address_space(1))) void*)g,
        (__attribute__((address_space(3))) void*)l, 16, 0, 0);
}

// ---------------- weight transpose + cast: W[K][N] fp32 -> Wt[N][K] bf16 ----
__global__ __launch_bounds__(256) void tcast_k(const float* __restrict__ W,
                                               short* __restrict__ Wt,
                                               int K, int N) {
    __shared__ float tile[32][33];
    int tx = threadIdx.x, ty = threadIdx.y;
    int n0 = blockIdx.x * 32, k0 = blockIdx.y * 32;
#pragma unroll
    for (int i = 0; i < 4; ++i)
        tile[ty + i * 8][tx] = W[(size_t)(k0 + ty + i * 8) * N + n0 + tx];
    __syncthreads();
#pragma unroll
    for (int i = 0; i < 4; ++i)
        Wt[(size_t)(n0 + ty + i * 8) * K + k0 + tx] = f2bf(tile[tx][ty + i * 8]);
}

// ---------------- layernorm: fp32 [rows][512] -> bf16, one wave per row -----
__global__ __launch_bounds__(256) void ln_k(const float* __restrict__ X,
                                            const float* __restrict__ g,
                                            const float* __restrict__ bta,
                                            short* __restrict__ Y) {
    int t = threadIdx.x;
    int wv = t >> 6, ln = t & 63;
    size_t row = (size_t)blockIdx.x * 4 + wv;
    const float* xr = X + row * DM;
    float4 v0 = *(const float4*)(xr + ln * 4);
    float4 v1 = *(const float4*)(xr + 256 + ln * 4);
    float s = v0.x + v0.y + v0.z + v0.w + v1.x + v1.y + v1.z + v1.w;
    float q = v0.x * v0.x + v0.y * v0.y + v0.z * v0.z + v0.w * v0.w +
              v1.x * v1.x + v1.y * v1.y + v1.z * v1.z + v1.w * v1.w;
#pragma unroll
    for (int off = 1; off < 64; off <<= 1) {
        s += __shfl_xor(s, off);
        q += __shfl_xor(q, off);
    }
    float mean = s * (1.0f / 512.0f);
    float var = q * (1.0f / 512.0f) - mean * mean;
    float rstd = rsqrtf(var + 1e-5f);
    int c0 = ln * 4, c1 = 256 + ln * 4;
    ushort4 o0, o1;
    o0.x = (unsigned short)f2bf((v0.x - mean) * rstd * g[c0 + 0] + bta[c0 + 0]);
    o0.y = (unsigned short)f2bf((v0.y - mean) * rstd * g[c0 + 1] + bta[c0 + 1]);
    o0.z = (unsigned short)f2bf((v0.z - mean) * rstd * g[c0 + 2] + bta[c0 + 2]);
    o0.w = (unsigned short)f2bf((v0.w - mean) * rstd * g[c0 + 3] + bta[c0 + 3]);
    o1.x = (unsigned short)f2bf((v1.x - mean) * rstd * g[c1 + 0] + bta[c1 + 0]);
    o1.y = (unsigned short)f2bf((v1.y - mean) * rstd * g[c1 + 1] + bta[c1 + 1]);
    o1.z = (unsigned short)f2bf((v1.z - mean) * rstd * g[c1 + 2] + bta[c1 + 2]);
    o1.w = (unsigned short)f2bf((v1.w - mean) * rstd * g[c1 + 3] + bta[c1 + 3]);
    *(ushort4*)((unsigned short*)Y + row * DM + c0) = o0;
    *(ushort4*)((unsigned short*)Y + row * DM + c1) = o1;
}

// ---------------- GEMM: C[M][N] = A[M][K] * Bt[N][K]^T, bf16 MFMA ----------
// EPI 0: bf16 out = C + bias ; EPI 1: bf16 out = gelu(C+bias) ;
// EPI 2: fp32 out = res + (C + bias) * gamma ;
// EPI 3: qkv special: ldc=1024; q-cols scaled by 0.125*log2e; k-cols plain;
//        v-cols stored transposed to Cout2 as vT[b*8+h][d][key] bf16.
template <int EPI, int TN>
__global__ __launch_bounds__(256) void gemm_bt(const short* __restrict__ A,
                                               const short* __restrict__ Bt,
                                               const float* __restrict__ bias,
                                               const float* __restrict__ gamma,
                                               const float* __restrict__ res,
                                               void* __restrict__ Cout,
                                               short* __restrict__ Cout2,
                                               int M, int N, int K) {
    constexpr int NI = TN / 32;   // B-fragment sets per wave
    __shared__ __attribute__((aligned(16))) short As[128][32];
    __shared__ __attribute__((aligned(16))) short Bs[TN][32];
    int t = threadIdx.x;
    int w = t >> 6, ln = t & 63;
    int quad = ln >> 4, l15 = ln & 15;
    int n0 = blockIdx.x * TN, m0 = blockIdx.y * 128;
    int wm = (w & 1) * 64, wn = (w >> 1) * (TN / 2);

    int srow0 = w * 32 + (ln >> 2);     // A staging: rows w*32 .. w*32+32
    int srow1 = srow0 + 16;
    int srowB = w * 16 + (ln >> 2);     // B staging for TN=64
    int schunk = (ln & 3) * 8;
    const short* Ag0 = A + (size_t)(m0 + srow0) * K + schunk;
    const short* Ag1 = A + (size_t)(m0 + srow1) * K + schunk;

    f32x4 acc[4][NI];
#pragma unroll
    for (int i = 0; i < 4; ++i)
#pragma unroll
        for (int j = 0; j < NI; ++j) acc[i][j] = (f32x4){0.f, 0.f, 0.f, 0.f};

    for (int k0 = 0; k0 < K; k0 += 32) {
        __syncthreads();
        gl2lds16(Ag0 + k0, &As[srow0][schunk]);
        gl2lds16(Ag1 + k0, &As[srow1][schunk]);
        if (TN == 128) {
            gl2lds16(Bt + (size_t)(n0 + srow0) * K + k0 + schunk, &Bs[srow0 & (TN - 1)][schunk]);
            gl2lds16(Bt + (size_t)(n0 + srow1) * K + k0 + schunk, &Bs[srow1 & (TN - 1)][schunk]);
        } else {
            gl2lds16(Bt + (size_t)(n0 + srowB) * K + k0 + schunk, &Bs[srowB & (TN - 1)][schunk]);
        }
        __syncthreads();
        short8 af[4], bf[NI];
#pragma unroll
        for (int mi = 0; mi < 4; ++mi)
            af[mi] = *(const short8*)&As[wm + mi * 16 + l15][quad * 8];
#pragma unroll
        for (int ni = 0; ni < NI; ++ni)
            bf[ni] = *(const short8*)&Bs[wn + ni * 16 + l15][quad * 8];
#pragma unroll
        for (int mi = 0; mi < 4; ++mi)
#pragma unroll
            for (int ni = 0; ni < NI; ++ni)
                acc[mi][ni] = __builtin_amdgcn_mfma_f32_16x16x32_bf16(
                    af[mi], bf[ni], acc[mi][ni], 0, 0, 0);
    }

    if (EPI == 3 && n0 >= 1024) {
        // v-part: transposed store vT[(b*8+h)][d][key], 4 consecutive keys/lane
#pragma unroll
        for (int mi = 0; mi < 4; ++mi) {
#pragma unroll
            for (int ni = 0; ni < NI; ++ni) {
                int col = n0 + wn + ni * 16 + l15;
                int d = col - 1024, hh = d >> 6, dd = d & 63;
                int row0 = m0 + wm + mi * 16 + quad * 4;
                int bb = row0 >> 11, key = row0 & 2047;
                float bs = bias[col];
                ushort4 pk;
                pk.x = (unsigned short)f2bf(acc[mi][ni][0] + bs);
                pk.y = (unsigned short)f2bf(acc[mi][ni][1] + bs);
                pk.z = (unsigned short)f2bf(acc[mi][ni][2] + bs);
                pk.w = (unsigned short)f2bf(acc[mi][ni][3] + bs);
                *(ushort4*)&Cout2[((size_t)(bb * 8 + hh) * 64 + dd) * 2048 + key] = pk;
            }
        }
    } else {
#pragma unroll
        for (int mi = 0; mi < 4; ++mi) {
#pragma unroll
            for (int ni = 0; ni < NI; ++ni) {
#pragma unroll
                for (int r = 0; r < 4; ++r) {
                    int row = m0 + wm + mi * 16 + quad * 4 + r;
                    int col = n0 + wn + ni * 16 + l15;
                    float v = acc[mi][ni][r] + bias[col];
                    if (EPI == 0) {
                        ((short*)Cout)[(size_t)row * N + col] = f2bf(v);
                    } else if (EPI == 1) {
                        float gg = 0.5f * v * (1.0f + erff(v * 0.70710678118654752f));
                        ((short*)Cout)[(size_t)row * N + col] = f2bf(gg);
                    } else if (EPI == 2) {
                        ((float*)Cout)[(size_t)row * N + col] =
                            fmaf(v, gamma[col], res[(size_t)row * N + col]);
                    } else {  // EPI 3, q/k cols, ldc = 1024
                        float sc = (n0 < 512) ? 0.18033688f : 1.0f;  // 0.125*log2e
                        ((short*)Cout)[(size_t)row * 1024 + col] = f2bf(v * sc);
                    }
                }
            }
        }
    }
}

// ---------------- flash attention v4: block = (b, h, 64-q tile) -------------
// 256 thr / 4 waves, wave w = q rows [qt*64+w*16, +16). All tiles staged
// coalesced into XOR-swizzled LDS (conflict-free), next tile reg-prefetched.
// blockIdx = qt*32 + b*8 + h: batch-peers adjacent on same XCD -> bias L2
// dedup; K/V L2-resident. No-max softmax (exp2, scale pre-folded into Q);
// row-sums via ones-column MFMA.
__global__ __launch_bounds__(256, 4) void attn_k(const short* __restrict__ qkv,
                                                 const short* __restrict__ vT,
                                                 const float* __restrict__ bias,
                                                 short* __restrict__ Aout) {
    __shared__ __attribute__((aligned(16))) short Ks[64 * 64];
    __shared__ __attribute__((aligned(16))) short Vs[64 * 64];
    __shared__ __attribute__((aligned(16))) float Bsf[64 * 64];
    __shared__ __attribute__((aligned(16))) short Ps[4][16 * 64];
    int t = threadIdx.x;
    int w = t >> 6, ln = t & 63, quad = ln >> 4, l15 = ln & 15;
    int idx = blockIdx.x;
    int h = idx & 7, b = (idx >> 3) & 3, qt = idx >> 5;
    int qb = qt * 64 + w * 16;
    const size_t cbase = (size_t)b * SEQ * 1024;

    // Q fragment (B-operand), pre-scaled by 0.125*log2e in qkv epilogue
    const short* qrow = qkv + cbase + (size_t)(qb + l15) * 1024 + h * 64;
    short8 qf0 = *(const short8*)(qrow + quad * 8);
    short8 qf1 = *(const short8*)(qrow + 32 + quad * 8);

    // staging maps (coalesced global, swizzled LDS)
    int kr = t >> 3, kc = t & 7;                              // kr 0..31, kc 0..7
    const short* kg = qkv + cbase + 512 + h * 64 + kc * 8;    // + (j0+row)*1024
    const short* vg = vT + ((size_t)(b * 8 + h) * 64) * 2048 + kc * 8;  // + d*2048+j0
    int bq = t >> 2, bc = t & 3;                              // bq 0..63
    const float* bg = bias + (size_t)h * SEQ * SEQ + (size_t)(qt * 64 + bq) * SEQ + bc * 4;

    int kswz = ((kc ^ (kr & 7)) * 8);
    int kd0 = kr * 64 + kswz;          // (kr+32)&7 == kr&7
    int kd1 = kd0 + 32 * 64;
    int bofs[4];
#pragma unroll
    for (int r = 0; r < 4; ++r)
        bofs[r] = bq * 64 + (((r * 4 + bc) ^ (bq & 15)) * 4);

    short8 ones;
#pragma unroll
    for (int i = 0; i < 8; ++i) ones[i] = (short)0x3F80;  // bf16 1.0

    f32x4 o[4], ol;
#pragma unroll
    for (int db = 0; db < 4; ++db) o[db] = (f32x4){0.f, 0.f, 0.f, 0.f};
    ol = (f32x4){0.f, 0.f, 0.f, 0.f};

    int sw7 = l15 & 7;

    // ---- prefetch jt = 0 ----
    float4 pk0 = *(const float4*)(kg + (size_t)kr * 1024);
    float4 pk1 = *(const float4*)(kg + (size_t)(kr + 32) * 1024);
    float4 pv0 = *(const float4*)(vg + (size_t)kr * 2048);
    float4 pv1 = *(const float4*)(vg + (size_t)(kr + 32) * 2048);
    float4 pb0 = *(const float4*)(bg + 0);
    float4 pb1 = *(const float4*)(bg + 16);
    float4 pb2 = *(const float4*)(bg + 32);
    float4 pb3 = *(const float4*)(bg + 48);

    for (int jt = 0; jt < 32; ++jt) {
        __syncthreads();   // previous tiles fully consumed
        *(float4*)&Ks[kd0] = pk0;
        *(float4*)&Ks[kd1] = pk1;
        *(float4*)&Vs[kd0] = pv0;
        *(float4*)&Vs[kd1] = pv1;
        *(float4*)&Bsf[bofs[0]] = pb0;
        *(float4*)&Bsf[bofs[1]] = pb1;
        *(float4*)&Bsf[bofs[2]] = pb2;
        *(float4*)&Bsf[bofs[3]] = pb3;
        __syncthreads();
        // prefetch jt+1 (lands during compute; consumed at next iter's writes)
        int j1 = (jt < 31) ? (jt + 1) * 64 : jt * 64;
        pk0 = *(const float4*)(kg + (size_t)(j1 + kr) * 1024);
        pk1 = *(const float4*)(kg + (size_t)(j1 + kr + 32) * 1024);
        pv0 = *(const float4*)(vg + (size_t)kr * 2048 + j1);
        pv1 = *(const float4*)(vg + (size_t)(kr + 32) * 2048 + j1);
        pb0 = *(const float4*)(bg + j1);
        pb1 = *(const float4*)(bg + j1 + 16);
        pb2 = *(const float4*)(bg + j1 + 32);
        pb3 = *(const float4*)(bg + j1 + 48);

        // S^T = K Q^T : lane holds (key = ni*16 + quad*4 + r, q = l15)
        f32x4 s4[4];
#pragma unroll
        for (int ni = 0; ni < 4; ++ni) {
            short8 k0 = *(const short8*)&Ks[(ni * 16 + l15) * 64 + ((quad ^ sw7) * 8)];
            short8 k1 = *(const short8*)&Ks[(ni * 16 + l15) * 64 + (((4 + quad) ^ sw7) * 8)];
            s4[ni] = (f32x4){0.f, 0.f, 0.f, 0.f};
            s4[ni] = __builtin_amdgcn_mfma_f32_16x16x32_bf16(k0, qf0, s4[ni], 0, 0, 0);
            s4[ni] = __builtin_amdgcn_mfma_f32_16x16x32_bf16(k1, qf1, s4[ni], 0, 0, 0);
        }
        // softmax: p = exp2(s + bias*log2e); pack to bf16; swizzled P write
#pragma unroll
        for (int ni = 0; ni < 4; ++ni) {
            float4 bb = *(const float4*)&Bsf[(w * 16 + l15) * 64 + (((ni * 4 + quad) ^ l15) * 4)];
            float2 plo, phi;
            plo.x = exp2f(fmaf(bb.x, 1.44269504f, s4[ni][0]));
            plo.y = exp2f(fmaf(bb.y, 1.44269504f, s4[ni][1]));
            phi.x = exp2f(fmaf(bb.z, 1.44269504f, s4[ni][2]));
            phi.y = exp2f(fmaf(bb.w, 1.44269504f, s4[ni][3]));
            __hip_bfloat162 l2 = __float22bfloat162_rn(plo);
            __hip_bfloat162 h2 = __float22bfloat162_rn(phi);
            union { uint2 u; } pp;
            pp.u.x = *(unsigned*)&l2;
            pp.u.y = *(unsigned*)&h2;
            int c = ni * 2 + (quad >> 1);
            *(uint2*)&Ps[w][l15 * 64 + ((c ^ sw7) * 8) + (quad & 1) * 4] = pp.u;
        }
        // O += P V ; l += P 1  (wave-private Ps: lgkmcnt ordering, no barrier)
#pragma unroll
        for (int kk = 0; kk < 2; ++kk) {
            short8 ap = *(const short8*)&Ps[w][l15 * 64 + (((kk * 4 + quad) ^ sw7) * 8)];
#pragma unroll
            for (int db = 0; db < 4; ++db) {
                short8 vv = *(const short8*)&Vs[(db * 16 + l15) * 64 + (((kk * 4 + quad) ^ sw7) * 8)];
                o[db] = __builtin_amdgcn_mfma_f32_16x16x32_bf16(ap, vv, o[db], 0, 0, 0);
            }
            ol = __builtin_amdgcn_mfma_f32_16x16x32_bf16(ap, ones, ol, 0, 0, 0);
        }
    }
    // epilogue: O row q = qb + quad*4 + r, col d = db*16 + l15
#pragma unroll
    for (int r = 0; r < 4; ++r) {
        float inv = 1.0f / ol[r];
        int qrow_g = b * SEQ + qb + quad * 4 + r;
#pragma unroll
        for (int db = 0; db < 4; ++db) {
            Aout[(size_t)qrow_g * DM + h * 64 + db * 16 + l15] =
                f2bf(o[db][r] * inv);
        }
    }
}

extern "C" void kernel_launch(void* const* d_in, const int* in_sizes, int n_in,
                              void* d_out, int out_size, void* d_ws, size_t ws_size,
                              hipStream_t stream) {
    const float* x      = (const float*)d_in[0];
    const float* bias   = (const float*)d_in[1];
    const float* qkv_w  = (const float*)d_in[2];
    const float* qkv_b  = (const float*)d_in[3];
    const float* out_w  = (const float*)d_in[4];
    const float* out_b  = (const float*)d_in[5];
    const float* ln1_w  = (const float*)d_in[6];
    const float* ln1_b  = (const float*)d_in[7];
    const float* ln2_w  = (const float*)d_in[8];
    const float* ln2_b  = (const float*)d_in[9];
    const float* ffn_w1 = (const float*)d_in[10];
    const float* ffn_b1 = (const float*)d_in[11];
    const float* ffn_w2 = (const float*)d_in[12];
    const float* ffn_b2 = (const float*)d_in[13];
    const float* gamma1 = (const float*)d_in[14];
    const float* gamma2 = (const float*)d_in[15];
    float* out = (float*)d_out;

    short* wqkvT = (short*)d_ws;                         // [1536][512]
    short* woutT = wqkvT + (size_t)1536 * 512;           // [512][512]
    short* w1T   = woutT + (size_t)512 * 512;            // [2048][512]
    short* w2T   = w1T + (size_t)2048 * 512;             // [512][2048]
    short* y1    = w2T + (size_t)512 * 2048;             // [8192][512]
    short* qkvB  = y1 + (size_t)ROWS * DM;               // [8192][1024] (q,k)
    short* vTb   = qkvB + (size_t)ROWS * 1024;           // [32][64][2048] (v^T)
    short* aoutB = vTb + (size_t)32 * 64 * 2048;         // [8192][512]
    float* x1    = (float*)(aoutB + (size_t)ROWS * DM);  // [8192][512] fp32
    short* hB    = qkvB;  // ffn hidden [8192][2048] reuses qkvB+vT+aoutB

    tcast_k<<<dim3(1536 / 32, 512 / 32), dim3(32, 8), 0, stream>>>(qkv_w, wqkvT, 512, 1536);
    tcast_k<<<dim3(512 / 32, 512 / 32), dim3(32, 8), 0, stream>>>(out_w, woutT, 512, 512);
    tcast_k<<<dim3(2048 / 32, 512 / 32), dim3(32, 8), 0, stream>>>(ffn_w1, w1T, 512, 2048);
    tcast_k<<<dim3(512 / 32, 2048 / 32), dim3(32, 8), 0, stream>>>(ffn_w2, w2T, 2048, 512);

    ln_k<<<ROWS / 4, 256, 0, stream>>>(x, ln1_w, ln1_b, y1);
    gemm_bt<3, 128><<<dim3(1536 / 128, ROWS / 128), 256, 0, stream>>>(
        y1, wqkvT, qkv_b, nullptr, nullptr, qkvB, vTb, ROWS, 1536, 512);
    attn_k<<<1024, 256, 0, stream>>>(qkvB, vTb, bias, aoutB);
    gemm_bt<2, 64><<<dim3(512 / 64, ROWS / 128), 256, 0, stream>>>(
        aoutB, woutT, out_b, gamma1, x, x1, nullptr, ROWS, 512, 512);
    ln_k<<<ROWS / 4, 256, 0, stream>>>(x1, ln2_w, ln2_b, y1);
    gemm_bt<1, 128><<<dim3(2048 / 128, ROWS / 128), 256, 0, stream>>>(
        y1, w1T, ffn_b1, nullptr, nullptr, hB, nullptr, ROWS, 2048, 512);
    gemm_bt<2, 64><<<dim3(512 / 64, ROWS / 128), 256, 0, stream>>>(
        hB, w2T, ffn_b2, gamma2, x1, out, nullptr, ROWS, 512, 2048);
}

// Round 5
// 441.872 us; speedup vs baseline: 1.4267x; 1.0113x over previous
//
#include <hip/hip_runtime.h>
#include <hip/hip_bf16.h>
#include <math.h>

#define SEQ 2048
#define BATCH 4
#define DM 512
#define NH 8
#define HD 64
#define HID 2048
#define ROWS (BATCH * SEQ)

typedef __attribute__((ext_vector_type(8))) short short8;
typedef __attribute__((ext_vector_type(4))) float f32x4;

__device__ __forceinline__ short f2bf(float f) {
    unsigned u = __float_as_uint(f);
    u += 0x7fff + ((u >> 16) & 1);   // RNE
    return (short)(u >> 16);
}

// async global->LDS DMA, 16 B per lane; LDS dest must be wave-uniform base + lane*16
__device__ __forceinline__ void gl2lds16(const void* g, void* l) {
    __builtin_amdgcn_global_load_lds(
        (const __attribute__((address_space(1))) void*)g,
        (__attribute__((address_space(3))) void*)l, 16, 0, 0);
}

// ------------- fused weight transpose+cast: 4 matrices, one launch ----------
__global__ __launch_bounds__(256) void tcast_all(
    const float* __restrict__ qkv_w, const float* __restrict__ out_w,
    const float* __restrict__ w1, const float* __restrict__ w2,
    short* __restrict__ o_qkv, short* __restrict__ o_out,
    short* __restrict__ o_w1, short* __restrict__ o_w2) {
    __shared__ float tile[32][33];
    int id = blockIdx.x;
    const float* W; short* O; int K, N;
    if (id < 768)       { W = qkv_w; O = o_qkv; K = 512;  N = 1536; }
    else if (id < 1024) { W = out_w; O = o_out; K = 512;  N = 512;  id -= 768; }
    else if (id < 2048) { W = w1;    O = o_w1;  K = 512;  N = 2048; id -= 1024; }
    else                { W = w2;    O = o_w2;  K = 2048; N = 512;  id -= 2048; }
    int tn = N / 32;
    int n0 = (id % tn) * 32, k0 = (id / tn) * 32;
    int tx = threadIdx.x, ty = threadIdx.y;
#pragma unroll
    for (int i = 0; i < 4; ++i)
        tile[ty + i * 8][tx] = W[(size_t)(k0 + ty + i * 8) * N + n0 + tx];
    __syncthreads();
#pragma unroll
    for (int i = 0; i < 4; ++i)
        O[(size_t)(n0 + ty + i * 8) * K + k0 + tx] = f2bf(tile[tx][ty + i * 8]);
}

// ---------------- layernorm: fp32 [rows][512] -> bf16, one wave per row -----
__global__ __launch_bounds__(256) void ln_k(const float* __restrict__ X,
                                            const float* __restrict__ g,
                                            const float* __restrict__ bta,
                                            short* __restrict__ Y) {
    int t = threadIdx.x;
    int wv = t >> 6, ln = t & 63;
    size_t row = (size_t)blockIdx.x * 4 + wv;
    const float* xr = X + row * DM;
    float4 v0 = *(const float4*)(xr + ln * 4);
    float4 v1 = *(const float4*)(xr + 256 + ln * 4);
    float s = v0.x + v0.y + v0.z + v0.w + v1.x + v1.y + v1.z + v1.w;
    float q = v0.x * v0.x + v0.y * v0.y + v0.z * v0.z + v0.w * v0.w +
              v1.x * v1.x + v1.y * v1.y + v1.z * v1.z + v1.w * v1.w;
#pragma unroll
    for (int off = 1; off < 64; off <<= 1) {
        s += __shfl_xor(s, off);
        q += __shfl_xor(q, off);
    }
    float mean = s * (1.0f / 512.0f);
    float var = q * (1.0f / 512.0f) - mean * mean;
    float rstd = rsqrtf(var + 1e-5f);
    int c0 = ln * 4, c1 = 256 + ln * 4;
    ushort4 o0, o1;
    o0.x = (unsigned short)f2bf((v0.x - mean) * rstd * g[c0 + 0] + bta[c0 + 0]);
    o0.y = (unsigned short)f2bf((v0.y - mean) * rstd * g[c0 + 1] + bta[c0 + 1]);
    o0.z = (unsigned short)f2bf((v0.z - mean) * rstd * g[c0 + 2] + bta[c0 + 2]);
    o0.w = (unsigned short)f2bf((v0.w - mean) * rstd * g[c0 + 3] + bta[c0 + 3]);
    o1.x = (unsigned short)f2bf((v1.x - mean) * rstd * g[c1 + 0] + bta[c1 + 0]);
    o1.y = (unsigned short)f2bf((v1.y - mean) * rstd * g[c1 + 1] + bta[c1 + 1]);
    o1.z = (unsigned short)f2bf((v1.z - mean) * rstd * g[c1 + 2] + bta[c1 + 2]);
    o1.w = (unsigned short)f2bf((v1.w - mean) * rstd * g[c1 + 3] + bta[c1 + 3]);
    *(ushort4*)((unsigned short*)Y + row * DM + c0) = o0;
    *(ushort4*)((unsigned short*)Y + row * DM + c1) = o1;
}

// ---------------- GEMM: C[M][N] = A[M][K] * Bt[N][K]^T, bf16 MFMA ----------
// BK=64 via dual 32-k sub-buffers (m97 bank pattern preserved; half the
// barriers of BK=32).
// EPI 0: bf16 out = C + bias ; EPI 1: bf16 out = gelu_tanh(C+bias) ;
// EPI 2: fp32 out = res + (C + bias) * gamma ;
// EPI 3: qkv special: ldc=1024; q-cols scaled by 0.125*log2e; k-cols plain;
//        v-cols stored transposed to Cout2 as vT[b*8+h][d][key] bf16.
template <int EPI, int TN>
__global__ __launch_bounds__(256) void gemm_bt(const short* __restrict__ A,
                                               const short* __restrict__ Bt,
                                               const float* __restrict__ bias,
                                               const float* __restrict__ gamma,
                                               const float* __restrict__ res,
                                               void* __restrict__ Cout,
                                               short* __restrict__ Cout2,
                                               int M, int N, int K) {
    constexpr int NI = TN / 32;   // B-fragment sets per wave
    __shared__ __attribute__((aligned(16))) short As0[128][32];
    __shared__ __attribute__((aligned(16))) short As1[128][32];
    __shared__ __attribute__((aligned(16))) short Bs0[TN][32];
    __shared__ __attribute__((aligned(16))) short Bs1[TN][32];
    int t = threadIdx.x;
    int w = t >> 6, ln = t & 63;
    int quad = ln >> 4, l15 = ln & 15;
    int n0 = blockIdx.x * TN, m0 = blockIdx.y * 128;
    int wm = (w & 1) * 64, wn = (w >> 1) * (TN / 2);

    int srow0 = w * 32 + (ln >> 2);     // A staging rows
    int srow1 = srow0 + 16;
    int srowB = w * 16 + (ln >> 2);     // B staging for TN=64
    int schunk = (ln & 3) * 8;
    const short* Ag0 = A + (size_t)(m0 + srow0) * K + schunk;
    const short* Ag1 = A + (size_t)(m0 + srow1) * K + schunk;
    const short* Bg0 = Bt + (size_t)(n0 + srow0) * K + schunk;
    const short* Bg1 = Bt + (size_t)(n0 + srow1) * K + schunk;
    const short* BgB = Bt + (size_t)(n0 + srowB) * K + schunk;

    f32x4 acc[4][NI];
#pragma unroll
    for (int i = 0; i < 4; ++i)
#pragma unroll
        for (int j = 0; j < NI; ++j) acc[i][j] = (f32x4){0.f, 0.f, 0.f, 0.f};

    for (int k0 = 0; k0 < K; k0 += 64) {
        __syncthreads();
        gl2lds16(Ag0 + k0, &As0[srow0][schunk]);
        gl2lds16(Ag1 + k0, &As0[srow1][schunk]);
        gl2lds16(Ag0 + k0 + 32, &As1[srow0][schunk]);
        gl2lds16(Ag1 + k0 + 32, &As1[srow1][schunk]);
        if (TN == 128) {
            gl2lds16(Bg0 + k0, &Bs0[srow0 & (TN - 1)][schunk]);
            gl2lds16(Bg1 + k0, &Bs0[srow1 & (TN - 1)][schunk]);
            gl2lds16(Bg0 + k0 + 32, &Bs1[srow0 & (TN - 1)][schunk]);
            gl2lds16(Bg1 + k0 + 32, &Bs1[srow1 & (TN - 1)][schunk]);
        } else {
            gl2lds16(BgB + k0, &Bs0[srowB & (TN - 1)][schunk]);
            gl2lds16(BgB + k0 + 32, &Bs1[srowB & (TN - 1)][schunk]);
        }
        __syncthreads();
        {
            short8 af[4], bf[NI];
#pragma unroll
            for (int mi = 0; mi < 4; ++mi)
                af[mi] = *(const short8*)&As0[wm + mi * 16 + l15][quad * 8];
#pragma unroll
            for (int ni = 0; ni < NI; ++ni)
                bf[ni] = *(const short8*)&Bs0[wn + ni * 16 + l15][quad * 8];
#pragma unroll
            for (int mi = 0; mi < 4; ++mi)
#pragma unroll
                for (int ni = 0; ni < NI; ++ni)
                    acc[mi][ni] = __builtin_amdgcn_mfma_f32_16x16x32_bf16(
                        af[mi], bf[ni], acc[mi][ni], 0, 0, 0);
        }
        {
            short8 af[4], bf[NI];
#pragma unroll
            for (int mi = 0; mi < 4; ++mi)
                af[mi] = *(const short8*)&As1[wm + mi * 16 + l15][quad * 8];
#pragma unroll
            for (int ni = 0; ni < NI; ++ni)
                bf[ni] = *(const short8*)&Bs1[wn + ni * 16 + l15][quad * 8];
#pragma unroll
            for (int mi = 0; mi < 4; ++mi)
#pragma unroll
                for (int ni = 0; ni < NI; ++ni)
                    acc[mi][ni] = __builtin_amdgcn_mfma_f32_16x16x32_bf16(
                        af[mi], bf[ni], acc[mi][ni], 0, 0, 0);
        }
    }

    if (EPI == 3 && n0 >= 1024) {
        // v-part: transposed store vT[(b*8+h)][d][key], 4 consecutive keys/lane
#pragma unroll
        for (int mi = 0; mi < 4; ++mi) {
#pragma unroll
            for (int ni = 0; ni < NI; ++ni) {
                int col = n0 + wn + ni * 16 + l15;
                int d = col - 1024, hh = d >> 6, dd = d & 63;
                int row0 = m0 + wm + mi * 16 + quad * 4;
                int bb = row0 >> 11, key = row0 & 2047;
                float bs = bias[col];
                ushort4 pk;
                pk.x = (unsigned short)f2bf(acc[mi][ni][0] + bs);
                pk.y = (unsigned short)f2bf(acc[mi][ni][1] + bs);
                pk.z = (unsigned short)f2bf(acc[mi][ni][2] + bs);
                pk.w = (unsigned short)f2bf(acc[mi][ni][3] + bs);
                *(ushort4*)&Cout2[((size_t)(bb * 8 + hh) * 64 + dd) * 2048 + key] = pk;
            }
        }
    } else {
#pragma unroll
        for (int mi = 0; mi < 4; ++mi) {
#pragma unroll
            for (int ni = 0; ni < NI; ++ni) {
#pragma unroll
                for (int r = 0; r < 4; ++r) {
                    int row = m0 + wm + mi * 16 + quad * 4 + r;
                    int col = n0 + wn + ni * 16 + l15;
                    float v = acc[mi][ni][r] + bias[col];
                    if (EPI == 0) {
                        ((short*)Cout)[(size_t)row * N + col] = f2bf(v);
                    } else if (EPI == 1) {
                        // gelu_tanh = v * sigmoid(2*0.79788456*(v+0.044715 v^3))
                        float u = v * fmaf(v * v, 0.0713548162f, 1.59576912f);
                        float gg = v / (1.0f + __expf(-u));
                        ((short*)Cout)[(size_t)row * N + col] = f2bf(gg);
                    } else if (EPI == 2) {
                        ((float*)Cout)[(size_t)row * N + col] =
                            fmaf(v, gamma[col], res[(size_t)row * N + col]);
                    } else {  // EPI 3, q/k cols, ldc = 1024
                        float sc = (n0 < 512) ? 0.18033688f : 1.0f;  // 0.125*log2e
                        ((short*)Cout)[(size_t)row * 1024 + col] = f2bf(v * sc);
                    }
                }
            }
        }
    }
}

// ---------------- flash attention v5: block = (b, h, 64-q tile) -------------
// 256 thr / 4 waves. K/V staged coalesced into XOR-swizzled LDS; bias read
// DIRECTLY from global as C-layout float4 (no LDS round-trip, no barrier
// coupling), register-prefetched one jt ahead. blockIdx = qt*32 + b*8 + h:
// batch-peers adjacent on the same XCD -> bias L2 dedup. No-max softmax
// (exp2, scale pre-folded into Q); row-sums via ones-column MFMA.
__global__ __launch_bounds__(256, 4) void attn_k(const short* __restrict__ qkv,
                                                 const short* __restrict__ vT,
                                                 const float* __restrict__ bias,
                                                 short* __restrict__ Aout) {
    __shared__ __attribute__((aligned(16))) short Ks[64 * 64];
    __shared__ __attribute__((aligned(16))) short Vs[64 * 64];
    __shared__ __attribute__((aligned(16))) short Ps[4][16 * 64];
    int t = threadIdx.x;
    int w = t >> 6, ln = t & 63, quad = ln >> 4, l15 = ln & 15;
    int idx = blockIdx.x;
    int h = idx & 7, b = (idx >> 3) & 3, qt = idx >> 5;
    int qb = qt * 64 + w * 16;
    const size_t cbase = (size_t)b * SEQ * 1024;

    // Q fragment (B-operand), pre-scaled by 0.125*log2e in qkv epilogue
    const short* qrow = qkv + cbase + (size_t)(qb + l15) * 1024 + h * 64;
    short8 qf0 = *(const short8*)(qrow + quad * 8);
    short8 qf1 = *(const short8*)(qrow + 32 + quad * 8);

    // staging maps (coalesced global, swizzled LDS)
    int kr = t >> 3, kc = t & 7;                              // kr 0..31, kc 0..7
    const short* kg = qkv + cbase + 512 + h * 64 + kc * 8;    // + (j0+row)*1024
    const short* vg = vT + ((size_t)(b * 8 + h) * 64) * 2048 + kc * 8;  // + d*2048+j0
    int kswz = ((kc ^ (kr & 7)) * 8);
    int kd0 = kr * 64 + kswz;          // (kr+32)&7 == kr&7
    int kd1 = kd0 + 32 * 64;

    // bias: direct global, C-layout float4 (keys ni*16+quad*4.. for q = l15)
    const float* bias_q = bias + (size_t)h * SEQ * SEQ +
                          (size_t)(qb + l15) * SEQ + quad * 4;

    short8 ones;
#pragma unroll
    for (int i = 0; i < 8; ++i) ones[i] = (short)0x3F80;  // bf16 1.0

    f32x4 o[4], ol;
#pragma unroll
    for (int db = 0; db < 4; ++db) o[db] = (f32x4){0.f, 0.f, 0.f, 0.f};
    ol = (f32x4){0.f, 0.f, 0.f, 0.f};

    int sw7 = l15 & 7;

    // ---- prefetch jt = 0 ----
    float4 pk0 = *(const float4*)(kg + (size_t)kr * 1024);
    float4 pk1 = *(const float4*)(kg + (size_t)(kr + 32) * 1024);
    float4 pv0 = *(const float4*)(vg + (size_t)kr * 2048);
    float4 pv1 = *(const float4*)(vg + (size_t)(kr + 32) * 2048);
    float4 bbc[4];
#pragma unroll
    for (int ni = 0; ni < 4; ++ni)
        bbc[ni] = *(const float4*)(bias_q + ni * 16);

    for (int jt = 0; jt < 32; ++jt) {
        __syncthreads();   // previous tiles fully consumed
        *(float4*)&Ks[kd0] = pk0;
        *(float4*)&Ks[kd1] = pk1;
        *(float4*)&Vs[kd0] = pv0;
        *(float4*)&Vs[kd1] = pv1;
        __syncthreads();
        // prefetch K/V(jt+1) (lands during compute)
        int j1 = (jt < 31) ? (jt + 1) * 64 : jt * 64;
        pk0 = *(const float4*)(kg + (size_t)(j1 + kr) * 1024);
        pk1 = *(const float4*)(kg + (size_t)(j1 + kr + 32) * 1024);
        pv0 = *(const float4*)(vg + (size_t)kr * 2048 + j1);
        pv1 = *(const float4*)(vg + (size_t)(kr + 32) * 2048 + j1);

        // S^T = K Q^T : lane holds (key = ni*16 + quad*4 + r, q = l15)
        f32x4 s4[4];
#pragma unroll
        for (int ni = 0; ni < 4; ++ni) {
            short8 k0 = *(const short8*)&Ks[(ni * 16 + l15) * 64 + ((quad ^ sw7) * 8)];
            short8 k1 = *(const short8*)&Ks[(ni * 16 + l15) * 64 + (((4 + quad) ^ sw7) * 8)];
            s4[ni] = (f32x4){0.f, 0.f, 0.f, 0.f};
            s4[ni] = __builtin_amdgcn_mfma_f32_16x16x32_bf16(k0, qf0, s4[ni], 0, 0, 0);
            s4[ni] = __builtin_amdgcn_mfma_f32_16x16x32_bf16(k1, qf1, s4[ni], 0, 0, 0);
        }
        // softmax: p = exp2(s + bias*log2e); pack bf16; swizzled P write.
        // bias for jt+1 prefetched right after last use of bbc[ni].
#pragma unroll
        for (int ni = 0; ni < 4; ++ni) {
            float4 bb = bbc[ni];
            float2 plo, phi;
            plo.x = exp2f(fmaf(bb.x, 1.44269504f, s4[ni][0]));
            plo.y = exp2f(fmaf(bb.y, 1.44269504f, s4[ni][1]));
            phi.x = exp2f(fmaf(bb.z, 1.44269504f, s4[ni][2]));
            phi.y = exp2f(fmaf(bb.w, 1.44269504f, s4[ni][3]));
            bbc[ni] = *(const float4*)(bias_q + j1 + ni * 16);
            __hip_bfloat162 l2 = __float22bfloat162_rn(plo);
            __hip_bfloat162 h2 = __float22bfloat162_rn(phi);
            union { uint2 u; } pp;
            pp.u.x = *(unsigned*)&l2;
            pp.u.y = *(unsigned*)&h2;
            int c = ni * 2 + (quad >> 1);
            *(uint2*)&Ps[w][l15 * 64 + ((c ^ sw7) * 8) + (quad & 1) * 4] = pp.u;
        }
        // O += P V ; l += P 1  (wave-private Ps: lgkmcnt ordering, no barrier)
#pragma unroll
        for (int kk = 0; kk < 2; ++kk) {
            short8 ap = *(const short8*)&Ps[w][l15 * 64 + (((kk * 4 + quad) ^ sw7) * 8)];
#pragma unroll
            for (int db = 0; db < 4; ++db) {
                short8 vv = *(const short8*)&Vs[(db * 16 + l15) * 64 + (((kk * 4 + quad) ^ sw7) * 8)];
                o[db] = __builtin_amdgcn_mfma_f32_16x16x32_bf16(ap, vv, o[db], 0, 0, 0);
            }
            ol = __builtin_amdgcn_mfma_f32_16x16x32_bf16(ap, ones, ol, 0, 0, 0);
        }
    }
    // epilogue: O row q = qb + quad*4 + r, col d = db*16 + l15
#pragma unroll
    for (int r = 0; r < 4; ++r) {
        float inv = 1.0f / ol[r];
        int qrow_g = b * SEQ + qb + quad * 4 + r;
#pragma unroll
        for (int db = 0; db < 4; ++db) {
            Aout[(size_t)qrow_g * DM + h * 64 + db * 16 + l15] =
                f2bf(o[db][r] * inv);
        }
    }
}

extern "C" void kernel_launch(void* const* d_in, const int* in_sizes, int n_in,
                              void* d_out, int out_size, void* d_ws, size_t ws_size,
                              hipStream_t stream) {
    const float* x      = (const float*)d_in[0];
    const float* bias   = (const float*)d_in[1];
    const float* qkv_w  = (const float*)d_in[2];
    const float* qkv_b  = (const float*)d_in[3];
    const float* out_w  = (const float*)d_in[4];
    const float* out_b  = (const float*)d_in[5];
    const float* ln1_w  = (const float*)d_in[6];
    const float* ln1_b  = (const float*)d_in[7];
    const float* ln2_w  = (const float*)d_in[8];
    const float* ln2_b  = (const float*)d_in[9];
    const float* ffn_w1 = (const float*)d_in[10];
    const float* ffn_b1 = (const float*)d_in[11];
    const float* ffn_w2 = (const float*)d_in[12];
    const float* ffn_b2 = (const float*)d_in[13];
    const float* gamma1 = (const float*)d_in[14];
    const float* gamma2 = (const float*)d_in[15];
    float* out = (float*)d_out;

    short* wqkvT = (short*)d_ws;                         // [1536][512]
    short* woutT = wqkvT + (size_t)1536 * 512;           // [512][512]
    short* w1T   = woutT + (size_t)512 * 512;            // [2048][512]
    short* w2T   = w1T + (size_t)2048 * 512;             // [512][2048]
    short* y1    = w2T + (size_t)512 * 2048;             // [8192][512]
    short* qkvB  = y1 + (size_t)ROWS * DM;               // [8192][1024] (q,k)
    short* vTb   = qkvB + (size_t)ROWS * 1024;           // [32][64][2048] (v^T)
    short* aoutB = vTb + (size_t)32 * 64 * 2048;         // [8192][512]
    float* x1    = (float*)(aoutB + (size_t)ROWS * DM);  // [8192][512] fp32
    short* hB    = qkvB;  // ffn hidden [8192][2048] reuses qkvB+vT

    tcast_all<<<3072, dim3(32, 8), 0, stream>>>(qkv_w, out_w, ffn_w1, ffn_w2,
                                                wqkvT, woutT, w1T, w2T);
    ln_k<<<ROWS / 4, 256, 0, stream>>>(x, ln1_w, ln1_b, y1);
    gemm_bt<3, 128><<<dim3(1536 / 128, ROWS / 128), 256, 0, stream>>>(
        y1, wqkvT, qkv_b, nullptr, nullptr, qkvB, vTb, ROWS, 1536, 512);
    attn_k<<<1024, 256, 0, stream>>>(qkvB, vTb, bias, aoutB);
    gemm_bt<2, 64><<<dim3(512 / 64, ROWS / 128), 256, 0, stream>>>(
        aoutB, woutT, out_b, gamma1, x, x1, nullptr, ROWS, 512, 512);
    ln_k<<<ROWS / 4, 256, 0, stream>>>(x1, ln2_w, ln2_b, y1);
    gemm_bt<1, 128><<<dim3(2048 / 128, ROWS / 128), 256, 0, stream>>>(
        y1, w1T, ffn_b1, nullptr, nullptr, hB, nullptr, ROWS, 2048, 512);
    gemm_bt<2, 64><<<dim3(512 / 64, ROWS / 128), 256, 0, stream>>>(
        hB, w2T, ffn_b2, gamma2, x1, out, nullptr, ROWS, 512, 2048);
}